// Round 1
// 254.507 us; speedup vs baseline: 1.2101x; 1.2101x over previous
//
#include <hip/hip_runtime.h>

// Problem constants (SVGA_7318624272625)
#define N_NODES 50000
#define N_EDGES 800000
#define F_IN    256
#define H_DIM   64
#define NB_SCAN ((N_NODES + 255) / 256)   // 196 dst buckets (256 nodes each)
#define TILE_A  4096                       // edges per binA block -> 196 blocks
#define EPT     (TILE_A / 256)             // edges per thread in binA (16)
#define MAXB    5632                       // max edges per bucket (avg 4081, +24 sigma)

typedef __attribute__((ext_vector_type(8))) short short8;
typedef __attribute__((ext_vector_type(4))) float floatx4;

__device__ __forceinline__ unsigned short f2bf(float f) {  // RNE fp32->bf16
  unsigned int u;
  __builtin_memcpy(&u, &f, 4);
  u += 0x7fffu + ((u >> 16) & 1u);
  return (unsigned short)(u >> 16);
}
__device__ __forceinline__ float bf2f(unsigned short s) {
  unsigned int v = ((unsigned int)s) << 16; float f; __builtin_memcpy(&f, &v, 4); return f;
}
__device__ __forceinline__ float bflo(unsigned int u) {
  unsigned int v = u << 16; float f; __builtin_memcpy(&f, &v, 4); return f;
}
__device__ __forceinline__ float bfhi(unsigned int u) {
  unsigned int v = u & 0xffff0000u; float f; __builtin_memcpy(&f, &v, 4); return f;
}

// Pack helper: W[K,64] (fp32) -> bf16 MFMA B-fragments, frag id
// f = (ks*4+c)*2+m ; lane L, j holds B[k=ks*32+(L>>4)*8+j][n=c*16+(L&15)].
template<int K>
__device__ __forceinline__ void pack_body(int t, const float* __restrict__ Wl,
                                          const float* __restrict__ Wr,
                                          unsigned short* __restrict__ Wb)
{
  int lane = t & 63;
  int f    = t >> 6;
  int m    = f & 1;
  int c    = (f >> 1) & 3;
  int ks   = f >> 3;
  const float* W = m ? Wr : Wl;
  int quad = lane >> 4, l15 = lane & 15;
  int col = c * 16 + l15;
  unsigned short u[8];
#pragma unroll
  for (int j = 0; j < 8; ++j) {
    int k = ks * 32 + quad * 8 + j;
    u[j] = f2bf(W[k * H_DIM + col]);
  }
  uint4 v;
  __builtin_memcpy(&v, u, 16);
  ((uint4*)Wb)[t] = v;
}

// Fused pack: blocks 0-15 pack W1 (4096 frags*lanes), 16-19 pack W2 (1024);
// block 0 also zeroes the loss slot and the bucket cursors (binA runs later
// on the same stream, so this ordering is safe).
__global__ __launch_bounds__(256) void pack_all_k(
    const float* __restrict__ W1l, const float* __restrict__ W1r,
    const float* __restrict__ W2l, const float* __restrict__ W2r,
    unsigned short* __restrict__ Wb1, unsigned short* __restrict__ Wb2,
    float* __restrict__ loss_slot, int* __restrict__ bcur)
{
  if (blockIdx.x == 0) {
    if (threadIdx.x == 0) loss_slot[0] = 0.f;
    if (threadIdx.x < NB_SCAN) bcur[threadIdx.x] = 0;
  }
  int b = blockIdx.x;
  if (b < 16) {
    pack_body<F_IN>(b * 256 + threadIdx.x, W1l, W1r, Wb1);
  } else {
    pack_body<H_DIM>((b - 16) * 256 + threadIdx.x, W2l, W2r, Wb2);
  }
}

// MFMA dual-GEMM: outl = bf16(X@Wl + bl), outr = bf16(X@Wr).
template<int K, bool XBF16>
__global__ __launch_bounds__(256, 4) void gemm_mfma_k(
    const void* __restrict__ X_,
    const unsigned short* __restrict__ Wb,
    const float* __restrict__ bl,
    unsigned short* __restrict__ outl, unsigned short* __restrict__ outr)
{
  constexpr int KP = K + 8;                 // padded row length (bf16 units)
  __shared__ unsigned short xs[64 * KP];
  const int row0 = blockIdx.x * 64;
  if (XBF16) {
    const uint4* X = (const uint4*)X_;      // row = K bf16 = K/8 uint4
    const int CH = K / 8;
    for (int i = threadIdx.x; i < 64 * CH; i += 256) {
      int r = i / CH, c = i % CH;
      int row = row0 + r;
      uint4 v = (row < N_NODES) ? X[(size_t)row * CH + c] : make_uint4(0, 0, 0, 0);
      *(uint4*)&xs[r * KP + c * 8] = v;
    }
  } else {
    const float4* X = (const float4*)X_;
    const int CH = K / 4;
    for (int i = threadIdx.x; i < 64 * CH; i += 256) {
      int r = i / CH, c = i % CH;
      int row = row0 + r;
      float4 v = (row < N_NODES) ? X[(size_t)row * CH + c]
                                 : make_float4(0.f, 0.f, 0.f, 0.f);
      unsigned int lo = (unsigned int)f2bf(v.x) | ((unsigned int)f2bf(v.y) << 16);
      unsigned int hi = (unsigned int)f2bf(v.z) | ((unsigned int)f2bf(v.w) << 16);
      *(uint2*)&xs[r * KP + c * 4] = make_uint2(lo, hi);
    }
  }
  __syncthreads();

  const int lane = threadIdx.x & 63;
  const int w    = threadIdx.x >> 6;
  const int quad = lane >> 4;
  const int l15  = lane & 15;
  const int rloc = w * 16 + l15;            // A-frag row

  floatx4 accl[4], accr[4];
#pragma unroll
  for (int c = 0; c < 4; ++c) { accl[c] = (floatx4)0.f; accr[c] = (floatx4)0.f; }

  const uint4* wbase = (const uint4*)Wb;
#pragma unroll
  for (int ks = 0; ks < K / 32; ++ks) {
    short8 af = *(const short8*)&xs[rloc * KP + ks * 32 + quad * 8];
#pragma unroll
    for (int c = 0; c < 4; ++c) {
      uint4 rl = wbase[((ks * 4 + c) * 2 + 0) * 64 + lane];
      uint4 rr = wbase[((ks * 4 + c) * 2 + 1) * 64 + lane];
      short8 bfl, bfr;
      __builtin_memcpy(&bfl, &rl, 16);
      __builtin_memcpy(&bfr, &rr, 16);
      accl[c] = __builtin_amdgcn_mfma_f32_16x16x32_bf16(af, bfl, accl[c], 0, 0, 0);
      accr[c] = __builtin_amdgcn_mfma_f32_16x16x32_bf16(af, bfr, accr[c], 0, 0, 0);
    }
  }
#pragma unroll
  for (int c = 0; c < 4; ++c) {
    int col = c * 16 + l15;
    float bias = bl[col];
#pragma unroll
    for (int reg = 0; reg < 4; ++reg) {
      int row = row0 + w * 16 + quad * 4 + reg;
      if (row < N_NODES) {
        outl[(size_t)row * H_DIM + col] = f2bf(accl[c][reg] + bias);
        outr[(size_t)row * H_DIM + col] = f2bf(accr[c][reg]);
      }
    }
  }
}

// binA: LDS-binned bucket scatter into fixed-stride bucket regions
// (ebuf[b*MAXB + cursor]); one global atomic per (block,bucket).
// No prepass needed: bcur zeroed by pack_all_k. ei read exactly once
// (src+dst cached in registers). 196 blocks -> full CU utilization.
__global__ __launch_bounds__(256) void binA_k(const int* __restrict__ ei,
                                              int* __restrict__ bcur,
                                              unsigned int* __restrict__ ebuf)
{
  __shared__ int lcnt[256];
  __shared__ int lofs[256];
  __shared__ int lstart[256];
  __shared__ int gstart[256];
  __shared__ int lcur[256];
  __shared__ unsigned int ldata[TILE_A];   // 16 KB
  const int t = threadIdx.x;
  const int e0 = blockIdx.x * TILE_A;
  lcnt[t] = 0;
  __syncthreads();
  int ss[EPT], ds[EPT];
#pragma unroll
  for (int j = 0; j < EPT; ++j) {
    int e = e0 + t + j * 256;              // coalesced
    if (e < N_EDGES) {
      ss[j] = ei[e];
      ds[j] = ei[N_EDGES + e];
      atomicAdd(&lcnt[ds[j] >> 8], 1);
    } else {
      ds[j] = -1;
    }
  }
  __syncthreads();
  int v = lcnt[t];
  lofs[t] = v;
  __syncthreads();
  for (int off = 1; off < 256; off <<= 1) {
    int u = (t >= off) ? lofs[t - off] : 0;
    __syncthreads();
    lofs[t] += u;
    __syncthreads();
  }
  lstart[t] = lofs[t] - v;
  lcur[t]   = lofs[t] - v;
  if (t < NB_SCAN && v > 0) gstart[t] = atomicAdd(&bcur[t], v);
  __syncthreads();
#pragma unroll
  for (int j = 0; j < EPT; ++j) {
    if (ds[j] >= 0) {
      int p = atomicAdd(&lcur[ds[j] >> 8], 1);
      ldata[p] = ((unsigned int)ss[j] << 8) | (unsigned int)(ds[j] & 255);
    }
  }
  __syncthreads();
  int w = t >> 6, lane = t & 63;
  for (int b = w; b < NB_SCAN; b += 4) {
    int st = lstart[b], len = lcnt[b];
    if (len == 0) continue;
    int g = gstart[b];
    unsigned int* dst = ebuf + (size_t)b * MAXB;
    for (int j = lane; j < len; j += 64) {
      int gp = g + j;
      if (gp < MAXB) dst[gp] = ldata[st + j];   // clamp: statistically unreachable
    }
  }
}

// binB: fused bucket-offset scan (over bcur) + per-bucket counting sort +
// CSR finalize: writes esrc (coalesced), edst (per-node runs), rowptr.
__global__ __launch_bounds__(256) void binB_k(const unsigned int* __restrict__ ebuf,
                                              const int* __restrict__ bcur,
                                              int* __restrict__ esrc,
                                              int* __restrict__ edst,
                                              int* __restrict__ rowptr)
{
  __shared__ int sc[256];                  // bucket-offset scan scratch
  __shared__ int ncnt[256];
  __shared__ int nscan[256];
  __shared__ int ncur[256];
  __shared__ int sh_se[2];                 // start, len
  __shared__ unsigned int sdata[MAXB];     // 22 KB
  const int b = blockIdx.x, t = threadIdx.x;
  // Bucket offsets: inclusive scan over clamped bucket lengths (196 ints).
  int bl = (t < NB_SCAN) ? min(bcur[t], MAXB) : 0;
  sc[t] = bl;
  __syncthreads();
  for (int off = 1; off < 256; off <<= 1) {
    int u = (t >= off) ? sc[t - off] : 0;
    __syncthreads();
    sc[t] += u;
    __syncthreads();
  }
  if (t == b) { sh_se[0] = sc[t] - bl; sh_se[1] = bl; }
  __syncthreads();
  const int start = sh_se[0], len = sh_se[1];
  const unsigned int* eb = ebuf + (size_t)b * MAXB;
  // Per-node histogram within the bucket.
  ncnt[t] = 0;
  __syncthreads();
  for (int i = t; i < len; i += 256) atomicAdd(&ncnt[eb[i] & 255], 1);
  __syncthreads();
  int v = ncnt[t];
  nscan[t] = v;
  __syncthreads();
  for (int off = 1; off < 256; off <<= 1) {
    int u = (t >= off) ? nscan[t - off] : 0;
    __syncthreads();
    nscan[t] += u;
    __syncthreads();
  }
  ncur[t] = nscan[t] - v;
  __syncthreads();
  for (int i = t; i < len; i += 256) {
    unsigned int e = eb[i];
    int p = atomicAdd(&ncur[e & 255], 1);
    sdata[p] = e >> 8;
  }
  __syncthreads();
  for (int i = t; i < len; i += 256) esrc[start + i] = (int)sdata[i];
  // edst expand + rowptr: node (b*256+t) owns [start+nscan[t]-v, start+nscan[t])
  int node = b * 256 + t;
  int s0 = start + nscan[t] - v;
  if (node < N_NODES) {
    rowptr[node] = s0;
    if (node == N_NODES - 1) rowptr[N_NODES] = s0 + v;   // == E
  }
  for (int j = 0; j < v; ++j) edst[s0 + j] = node;
}

// ---- Fused aggregation: wave per dst node, lane = feature, bf16 everywhere ----
__device__ __forceinline__ float agg_row_b(const int* __restrict__ esrc,
                                           const unsigned short* __restrict__ m,
                                           int b, int e, int lane)
{
  float a0 = 0.f, a1 = 0.f, a2 = 0.f, a3 = 0.f;
  float a4 = 0.f, a5 = 0.f, a6 = 0.f, a7 = 0.f;
  int i = b;
  for (; i + 8 <= e; i += 8) {
    int s0 = esrc[i],     s1 = esrc[i + 1], s2 = esrc[i + 2], s3 = esrc[i + 3];
    int s4 = esrc[i + 4], s5 = esrc[i + 5], s6 = esrc[i + 6], s7 = esrc[i + 7];
    a0 += bf2f(m[(size_t)s0 * H_DIM + lane]);
    a1 += bf2f(m[(size_t)s1 * H_DIM + lane]);
    a2 += bf2f(m[(size_t)s2 * H_DIM + lane]);
    a3 += bf2f(m[(size_t)s3 * H_DIM + lane]);
    a4 += bf2f(m[(size_t)s4 * H_DIM + lane]);
    a5 += bf2f(m[(size_t)s5 * H_DIM + lane]);
    a6 += bf2f(m[(size_t)s6 * H_DIM + lane]);
    a7 += bf2f(m[(size_t)s7 * H_DIM + lane]);
  }
  for (; i + 4 <= e; i += 4) {
    int s0 = esrc[i], s1 = esrc[i + 1], s2 = esrc[i + 2], s3 = esrc[i + 3];
    a0 += bf2f(m[(size_t)s0 * H_DIM + lane]);
    a1 += bf2f(m[(size_t)s1 * H_DIM + lane]);
    a2 += bf2f(m[(size_t)s2 * H_DIM + lane]);
    a3 += bf2f(m[(size_t)s3 * H_DIM + lane]);
  }
  for (; i < e; ++i) a0 += bf2f(m[(size_t)esrc[i] * H_DIM + lane]);
  return ((a0 + a1) + (a2 + a3)) + ((a4 + a5) + (a6 + a7));
}

// h = relu(mean m1 + xr) -> bf16
__global__ __launch_bounds__(256) void agg1_k(
    const int* __restrict__ rowptr, const int* __restrict__ esrc,
    const unsigned short* __restrict__ m, const unsigned short* __restrict__ xr,
    unsigned short* __restrict__ h)
{
  int gid = blockIdx.x * 256 + threadIdx.x;
  int row = gid >> 6, lane = gid & 63;
  if (row >= N_NODES) return;
  int b = rowptr[row], e = rowptr[row + 1];
  float acc = agg_row_b(esrc, m, b, e, lane);
  float dv = fmaxf((float)(e - b), 1.f);
  size_t o = (size_t)row * H_DIM + lane;
  h[o] = f2bf(fmaxf(acc / dv + bf2f(xr[o]), 0.f));
}

// z = unitnorm(mean m2 + hr) -> fp32 d_out + bf16 copy (decode gathers)
__global__ __launch_bounds__(256) void agg2_k(
    const int* __restrict__ rowptr, const int* __restrict__ esrc,
    const unsigned short* __restrict__ m, const unsigned short* __restrict__ hr,
    float* __restrict__ zout, unsigned short* __restrict__ zb)
{
  int gid = blockIdx.x * 256 + threadIdx.x;
  int row = gid >> 6, lane = gid & 63;
  if (row >= N_NODES) return;
  int b = rowptr[row], e = rowptr[row + 1];
  float acc = agg_row_b(esrc, m, b, e, lane);
  float dv = fmaxf((float)(e - b), 1.f);
  size_t o = (size_t)row * H_DIM + lane;
  float v = acc / dv + bf2f(hr[o]);
  float ss = v * v;
#pragma unroll
  for (int mm = 32; mm >= 1; mm >>= 1) ss += __shfl_xor(ss, mm, 64);
  float z = v * rsqrtf(fmaxf(ss, 1e-30f));
  zout[o] = z;
  zb[o] = f2bf(z);
}

// Decode: two edges per thread, CSR order, bf16 z rows; accumulates the mean
// BCE loss into loss_slot (zeroed by pack_all_k).
__global__ __launch_bounds__(256) void decode2_k(
    const int* __restrict__ esrc, const int* __restrict__ edst,
    const unsigned short* __restrict__ zb, float* __restrict__ loss_slot)
{
  int i0 = (blockIdx.x * 256 + threadIdx.x) * 2;
  float part = 0.f;
  if (i0 + 1 < N_EDGES) {
    int s0 = esrc[i0],     d0 = edst[i0];
    int s1 = esrc[i0 + 1], d1 = edst[i0 + 1];
    const uint4* zs0 = (const uint4*)(zb + (size_t)s0 * H_DIM);
    const uint4* zd0 = (const uint4*)(zb + (size_t)d0 * H_DIM);
    const uint4* zs1 = (const uint4*)(zb + (size_t)s1 * H_DIM);
    const uint4* zd1 = (const uint4*)(zb + (size_t)d1 * H_DIM);
    float p0 = 0.f, p1 = 0.f;
#pragma unroll 4
    for (int k = 0; k < 8; ++k) {          // 8 uint4 = 64 bf16 = full row
      uint4 a0 = zs0[k], b0 = zd0[k], a1 = zs1[k], b1 = zd1[k];
      unsigned int au0[4] = {a0.x, a0.y, a0.z, a0.w};
      unsigned int bu0[4] = {b0.x, b0.y, b0.z, b0.w};
      unsigned int au1[4] = {a1.x, a1.y, a1.z, a1.w};
      unsigned int bu1[4] = {b1.x, b1.y, b1.z, b1.w};
#pragma unroll
      for (int j = 0; j < 4; ++j) {
        p0 = fmaf(bflo(au0[j]), bflo(bu0[j]), p0);
        p0 = fmaf(bfhi(au0[j]), bfhi(bu0[j]), p0);
        p1 = fmaf(bflo(au1[j]), bflo(bu1[j]), p1);
        p1 = fmaf(bfhi(au1[j]), bfhi(bu1[j]), p1);
      }
    }
    part  = fmaxf(-p0, 0.f) + log1pf(expf(-fabsf(p0)));
    part += fmaxf(-p1, 0.f) + log1pf(expf(-fabsf(p1)));
  }
#pragma unroll
  for (int m = 32; m >= 1; m >>= 1) part += __shfl_xor(part, m, 64);
  __shared__ float sbuf[4];
  int lane = threadIdx.x & 63, w = threadIdx.x >> 6;
  if (lane == 0) sbuf[w] = part;
  __syncthreads();
  if (threadIdx.x == 0)
    atomicAdd(loss_slot, (sbuf[0] + sbuf[1] + sbuf[2] + sbuf[3]) * (1.0f / N_EDGES));
}

extern "C" void kernel_launch(void* const* d_in, const int* in_sizes, int n_in,
                              void* d_out, int out_size, void* d_ws, size_t ws_size,
                              hipStream_t stream)
{
  (void)in_sizes; (void)n_in; (void)out_size; (void)ws_size;
  const float* x   = (const float*)d_in[0];
  const int*   ei  = (const int*)d_in[1];
  const float* W1l = (const float*)d_in[2];
  const float* b1l = (const float*)d_in[3];
  const float* W1r = (const float*)d_in[4];
  const float* W2l = (const float*)d_in[5];
  const float* b2l = (const float*)d_in[6];
  const float* W2r = (const float*)d_in[7];
  float* out = (float*)d_out;  // fp32: z [N*H] ++ loss [1]
  float* loss_slot = out + (size_t)N_NODES * H_DIM;

  const size_t NH = (size_t)N_NODES * H_DIM;
  // uA = m1 then m2; uB = h then zb; uC = xr then hr (all bf16).
  unsigned short* uA = (unsigned short*)d_ws;   // NH ushort
  unsigned short* uB = uA + NH;                 // NH ushort
  unsigned short* uC = uB + NH;                 // NH ushort
  // Wb right after bf16 buffers: 19.2 MB offset is 16B-aligned (uint4 access).
  unsigned short* Wb1 = uC + NH;                             // 64 KB
  unsigned short* Wb2 = Wb1 + (F_IN / 32) * 4 * 2 * 64 * 8;  // 16 KB
  int* rowptr = (int*)(Wb2 + (H_DIM / 32) * 4 * 2 * 64 * 8); // N+1
  int* esrc   = rowptr + N_NODES + 1;   // E
  int* edst   = esrc + N_EDGES;         // E
  int* bcur   = edst + N_EDGES;         // NB_SCAN
  unsigned int* ebuf = (unsigned int*)(bcur + NB_SCAN);      // NB_SCAN*MAXB (4.4 MB)

  dim3 blk(256);
  dim3 g_tile((N_NODES + 63) / 64);
  dim3 g_edge2((N_EDGES / 2 + 255) / 256);
  dim3 g_node((N_NODES * 64 + 255) / 256);
  dim3 g_binA((N_EDGES + TILE_A - 1) / TILE_A);   // 196
  dim3 g_bin(NB_SCAN);                            // 196

  // Pack W1+W2 fragments (bf16) + zero loss slot + zero bucket cursors
  pack_all_k<<<dim3(20), blk, 0, stream>>>(W1l, W1r, W2l, W2r, Wb1, Wb2,
                                           loss_slot, bcur);
  // CSR build: LDS-binned bucket scatter -> fused scan + bucket sort + CSR
  binA_k<<<g_binA, blk, 0, stream>>>(ei, bcur, ebuf);
  binB_k<<<g_bin, blk, 0, stream>>>(ebuf, bcur, esrc, edst, rowptr);
  // Layer 1 (MFMA): m1 -> uA, xr -> uC (bf16)
  gemm_mfma_k<F_IN, false><<<g_tile, blk, 0, stream>>>(x, Wb1, b1l, uA, uC);
  agg1_k<<<g_node, blk, 0, stream>>>(rowptr, esrc, uA, uC, uB);
  // Layer 2 (MFMA, bf16 input): m2 -> uA, hr -> uC (bf16)
  gemm_mfma_k<H_DIM, true><<<g_tile, blk, 0, stream>>>(uB, Wb2, b2l, uA, uC);
  agg2_k<<<g_node, blk, 0, stream>>>(rowptr, esrc, uA, uC, out, uB);
  // Decode + loss (CSR order, bf16 gathers, 2 edges/thread)
  decode2_k<<<g_edge2, blk, 0, stream>>>(esrc, edst, uB, loss_slot);
}